// Round 7
// baseline (137.177 us; speedup 1.0000x reference)
//
#include <hip/hip_runtime.h>

#define HW 512
#define NSTATE (HW * HW)   // 262144
#define NC4_X 196608       // x as float4 (3*H*W/4)
#define NC4_POLROW 262144  // Wpol row stride in float4
#define NC4_V 65536        // v as float4

#define SPAN_MV 3072  // float4 per wave-span in mv_dual (48 KB), 64 spans/row
#define NSPAN_MV 64
#define CHUNK4 128                    // float4 per W chunk (2 KB)
#define NCHUNK_MV (SPAN_MV / CHUNK4)  // 24
#define SPAN_PV 2048                  // float4 per wave-span in mv_polv
#define NSPAN_PV 32
#define NCHUNK_PV (SPAN_PV / CHUNK4)  // 16
#define SPAN_ROP 1024

// ws layout (float offsets)
#define WS_PART1 0
#define WS_PARTPX 2048
#define WS_PARTPV 4096
#define WS_H2 5120
#define WS_P 5184
#define WS_RD (WS_P + NSTATE)
#define WS_V (WS_RD + NSTATE)

#define SGB __builtin_amdgcn_sched_group_barrier
#define VMCNT(n) asm volatile("s_waitcnt vmcnt(" #n ")" ::: "memory")

// Async global->LDS, 16B per lane, dest = wave-uniform base + lane*16.
__device__ __forceinline__ void gl_lds16(const float4* g, float4* l) {
  __builtin_amdgcn_global_load_lds(
      (const __attribute__((address_space(1))) void*)g,
      (__attribute__((address_space(3))) void*)l, 16, 0, 0);
}
__device__ __forceinline__ float dot4(float4 a, float4 b) {
  return a.x * b.x + a.y * b.y + a.z * b.z + a.w * b.w;
}

// ---------------------------------------------------------------------------
// K1: partials for W1@x and Wpol[:, x-cols]@x via global_load_lds.
// R6 lesson (Little's law): 1-chunk-deep pipeline -> ~13 KB/CU in flight ->
// ~3 TB/s ceiling. Fix: depth-4 ring, counted vmcnt(6) (3 chunks / 6 KB per
// wave in flight, never drained mid-loop), literal tail drain 4->2->0.
// Block = (m, span s, rowgroup g); 4 waves = 4 rows; 48 KB x-span shared.
// ---------------------------------------------------------------------------
__global__ __launch_bounds__(256) void mv_dual(
    const float4* __restrict__ W1, const float4* __restrict__ Wpol,
    const float4* __restrict__ x, float* __restrict__ part1,
    float* __restrict__ partPx) {
  __shared__ float4 xs[SPAN_MV];       // 48 KB
  __shared__ float4 wb[4][4][CHUNK4];  // 32 KB: per-wave depth-4 ring
  int b = blockIdx.x;  // [0,1024)
  int m = b >> 9, rest = b & 511, s = rest >> 3, g = rest & 7;
  int tid = threadIdx.x, wave = tid >> 6, lane = tid & 63;
  int row = g * 4 + wave;  // 0..31
  const float4* __restrict__ wp =
      (m ? (Wpol + (size_t)row * NC4_POLROW + NC4_V)
         : (W1 + (size_t)row * NC4_X)) +
      (size_t)s * SPAN_MV;
  const float4* __restrict__ xp = x + (size_t)s * SPAN_MV;
  // cooperative x-span stage: 12 x 1KB per wave
  for (int j = 0; j < 12; ++j) {
    int blk = wave * 12 + j;
    gl_lds16(xp + blk * 64 + lane, &xs[blk * 64]);
  }
  // prologue: W chunks 0..2
  for (int c = 0; c < 3; ++c) {
    gl_lds16(wp + c * CHUNK4 + lane, &wb[wave][c][0]);
    gl_lds16(wp + c * CHUNK4 + 64 + lane, &wb[wave][c][64]);
  }
  __syncthreads();  // one-time drain: x + chunks 0..2 resident
  float acc0 = 0.f, acc1 = 0.f;
  for (int i = 0; i < NCHUNK_MV; ++i) {
    if (i + 3 < NCHUNK_MV) {
      int t = i + 3, tb = t & 3;
      gl_lds16(wp + t * CHUNK4 + lane, &wb[wave][tb][0]);
      gl_lds16(wp + t * CHUNK4 + 64 + lane, &wb[wave][tb][64]);
      VMCNT(6);  // chunk i complete; chunks i+1..i+3 (6 ops) in flight
    } else if (i + 3 == NCHUNK_MV) {
      VMCNT(4);
    } else if (i + 2 == NCHUNK_MV) {
      VMCNT(2);
    } else {
      VMCNT(0);
    }
    __builtin_amdgcn_sched_barrier(0);
    int cb = i & 3;
    float4 w0 = wb[wave][cb][lane];
    float4 w1 = wb[wave][cb][64 + lane];
    float4 x0 = xs[i * CHUNK4 + lane];
    float4 x1 = xs[i * CHUNK4 + 64 + lane];
    acc0 += dot4(w0, x0);
    acc1 += dot4(w1, x1);
  }
  float a = acc0 + acc1;
  a += __shfl_xor(a, 32);
  a += __shfl_xor(a, 16);
  a += __shfl_xor(a, 8);
  a += __shfl_xor(a, 4);
  a += __shfl_xor(a, 2);
  a += __shfl_xor(a, 1);
  if (lane == 0) (m ? partPx : part1)[s * 32 + row] = a;
}

// ---------------------------------------------------------------------------
// K5: partials for Wpol[:, v-cols] @ v. Same depth-4 ring template.
// ---------------------------------------------------------------------------
__global__ __launch_bounds__(256) void mv_polv(
    const float4* __restrict__ Wpol, const float4* __restrict__ v,
    float* __restrict__ partPv) {
  __shared__ float4 xs[SPAN_PV];       // 32 KB
  __shared__ float4 wb[4][4][CHUNK4];  // 32 KB
  int b = blockIdx.x;  // [0,256)
  int s = b >> 3, g = b & 7;
  int tid = threadIdx.x, wave = tid >> 6, lane = tid & 63;
  int row = g * 4 + wave;
  const float4* __restrict__ wp =
      Wpol + (size_t)row * NC4_POLROW + (size_t)s * SPAN_PV;
  const float4* __restrict__ vp = v + (size_t)s * SPAN_PV;
  for (int j = 0; j < 8; ++j) {  // 8 x 1KB per wave
    int blk = wave * 8 + j;
    gl_lds16(vp + blk * 64 + lane, &xs[blk * 64]);
  }
  for (int c = 0; c < 3; ++c) {
    gl_lds16(wp + c * CHUNK4 + lane, &wb[wave][c][0]);
    gl_lds16(wp + c * CHUNK4 + 64 + lane, &wb[wave][c][64]);
  }
  __syncthreads();
  float acc0 = 0.f, acc1 = 0.f;
  for (int i = 0; i < NCHUNK_PV; ++i) {
    if (i + 3 < NCHUNK_PV) {
      int t = i + 3, tb = t & 3;
      gl_lds16(wp + t * CHUNK4 + lane, &wb[wave][tb][0]);
      gl_lds16(wp + t * CHUNK4 + 64 + lane, &wb[wave][tb][64]);
      VMCNT(6);
    } else if (i + 3 == NCHUNK_PV) {
      VMCNT(4);
    } else if (i + 2 == NCHUNK_PV) {
      VMCNT(2);
    } else {
      VMCNT(0);
    }
    __builtin_amdgcn_sched_barrier(0);
    int cb = i & 3;
    float4 w0 = wb[wave][cb][lane];
    float4 w1 = wb[wave][cb][64 + lane];
    float4 x0 = xs[i * CHUNK4 + lane];
    float4 x1 = xs[i * CHUNK4 + 64 + lane];
    acc0 += dot4(w0, x0);
    acc1 += dot4(w1, x1);
  }
  float a = acc0 + acc1;
  a += __shfl_xor(a, 32);
  a += __shfl_xor(a, 16);
  a += __shfl_xor(a, 8);
  a += __shfl_xor(a, 4);
  a += __shfl_xor(a, 2);
  a += __shfl_xor(a, 1);
  if (lane == 0) partPv[s * 32 + row] = a;
}

// ---------------------------------------------------------------------------
// finish_h: reduce part1[64][32] -> h1 = relu(W1@x+b1); h2 = relu(W2@h1+b2).
// ---------------------------------------------------------------------------
__global__ __launch_bounds__(256) void finish_h(
    const float* __restrict__ partials, const float* __restrict__ b1,
    const float* __restrict__ W2, const float* __restrict__ b2,
    float* __restrict__ h2out) {
  __shared__ float red[8][32];
  __shared__ float h1[32];
  int tid = threadIdx.x;
  int row = tid & 31, grp = tid >> 5;
  float s = 0.f;
  for (int b = grp; b < NSPAN_MV; b += 8) s += partials[b * 32 + row];
  red[grp][row] = s;
  __syncthreads();
  if (tid < 32) {
    float t = b1[tid];
    for (int g = 0; g < 8; ++g) t += red[g][tid];
    h1[tid] = fmaxf(t, 0.f);
  }
  __syncthreads();
  if (tid < 64) {
    float t = b2[tid];
    for (int k = 0; k < 32; ++k) t += W2[tid * 32 + k] * h1[k];
    h2out[tid] = fmaxf(t, 0.f);
  }
}

// ---------------------------------------------------------------------------
// rop: p = sig(Wp@h2+bp), rd = sig(Wri@h2+bri) - sig(Wro@h2+bro).
// Flat-span streaming (R5 version — unchanged, ~6 TB/s effective).
// ---------------------------------------------------------------------------
__global__ __launch_bounds__(256) void rop_kernel(
    const float4* __restrict__ Wro4, const float* __restrict__ bro,
    const float4* __restrict__ Wri4, const float* __restrict__ bri,
    const float4* __restrict__ Wp4, const float* __restrict__ bp,
    const float* __restrict__ h2, float* __restrict__ p_out,
    float* __restrict__ rd_out) {
  __shared__ float dots[4][3][64];
  int tid = threadIdx.x;
  int wave = tid >> 6, lane = tid & 63;
  int grp = lane >> 4;
  float4 h4 = ((const float4*)h2)[lane & 15];
  int span = blockIdx.x * 4 + wave;       // [0,4096)
  size_t base = (size_t)span * SPAN_ROP;  // first float4 of span
  const float4* mats[3] = {Wro4, Wri4, Wp4};
#pragma unroll
  for (int m = 0; m < 3; ++m) {
    const float4* __restrict__ W = mats[m] + base + lane;
#pragma unroll
    for (int batch = 0; batch < 2; ++batch) {
      float4 w[8];
#pragma unroll
      for (int j = 0; j < 8; ++j) w[j] = W[(batch * 8 + j) * 64];
      SGB(0x020, 8, 0);
      float part[8];
#pragma unroll
      for (int j = 0; j < 8; ++j)
        part[j] = w[j].x * h4.x + w[j].y * h4.y + w[j].z * h4.z + w[j].w * h4.w;
#pragma unroll
      for (int j = 0; j < 8; ++j) {
        part[j] += __shfl_xor(part[j], 8);
        part[j] += __shfl_xor(part[j], 4);
        part[j] += __shfl_xor(part[j], 2);
        part[j] += __shfl_xor(part[j], 1);
      }
      if ((lane & 15) == 0) {
#pragma unroll
        for (int j = 0; j < 8; ++j)
          dots[wave][m][(batch * 8 + j) * 4 + grp] = part[j];
      }
    }
  }
  __syncthreads();
  int o = blockIdx.x * 256 + tid;
  float dro = dots[tid >> 6][0][tid & 63] + bro[o];
  float dri = dots[tid >> 6][1][tid & 63] + bri[o];
  float dp = dots[tid >> 6][2][tid & 63] + bp[o];
  float sro = 1.f / (1.f + __expf(-dro));
  float sri = 1.f / (1.f + __expf(-dri));
  float pv = 1.f / (1.f + __expf(-dp));
  p_out[o] = pv;
  rd_out[o] = sri - sro;
}

// ---------------------------------------------------------------------------
// Value iteration, ONE launch, 1024 blocks. 16x16 tile + halo 10 in LDS,
// 10 local iterations; zero-padding semantics preserved.
// ---------------------------------------------------------------------------
#define TILE 16
#define HALO 10
#define LR 36  // TILE + 2*HALO
__global__ __launch_bounds__(256) void valiter_kernel(
    const float* __restrict__ p, const float* __restrict__ rd,
    float* __restrict__ vout) {
  __shared__ float u[LR + 2][LR + 3];
  __shared__ float pp[LR][LR + 1];
  __shared__ float rr[LR][LR + 1];
  __shared__ float vv[LR][LR + 1];
  int tid = threadIdx.x;
  int ti = blockIdx.x >> 5, tj = blockIdx.x & 31;
  int gi0 = ti * TILE - HALO, gj0 = tj * TILE - HALO;
  for (int idx = tid; idx < (LR + 2) * (LR + 3); idx += 256)
    ((float*)u)[idx] = 0.f;
  for (int idx = tid; idx < LR * LR; idx += 256) {
    int i = idx / LR, j = idx % LR;
    int gi = gi0 + i, gj = gj0 + j;
    bool ok = (gi >= 0) & (gi < HW) & (gj >= 0) & (gj < HW);
    pp[i][j] = ok ? p[gi * HW + gj] : 0.f;
    rr[i][j] = ok ? rd[gi * HW + gj] : 0.f;
    vv[i][j] = 0.f;
  }
  __syncthreads();
  for (int k = 0; k < 10; ++k) {
#pragma unroll
    for (int idx = tid; idx < LR * LR; idx += 256) {
      int i = idx / LR, j = idx % LR;
      u[i + 1][j + 1] = vv[i][j] * pp[i][j] + rr[i][j];
    }
    __syncthreads();
#pragma unroll
    for (int idx = tid; idx < LR * LR; idx += 256) {
      int i = idx / LR, j = idx % LR;
      float m = u[i][j];
      m = fmaxf(m, u[i][j + 1]);
      m = fmaxf(m, u[i][j + 2]);
      m = fmaxf(m, u[i + 1][j]);
      m = fmaxf(m, u[i + 1][j + 2]);
      m = fmaxf(m, u[i + 2][j]);
      m = fmaxf(m, u[i + 2][j + 1]);
      m = fmaxf(m, u[i + 2][j + 2]);
      vv[i][j] = m;
    }
    __syncthreads();
  }
  if (tid < TILE * TILE) {
    int a = tid >> 4, b = tid & 15;
    vout[(ti * TILE + a) * HW + tj * TILE + b] = vv[HALO + a][HALO + b];
  }
}

// ---------------------------------------------------------------------------
// finish_pol: hp = relu(bpol + sum partPx[64][32] + sum partPv[32][32]);
// logits = Whead@hp + bhead; softmax; out[8] = v[pos].
// ---------------------------------------------------------------------------
__global__ __launch_bounds__(256) void finish_pol(
    const float* __restrict__ partPx, const float* __restrict__ partPv,
    const float* __restrict__ bpol, const float* __restrict__ Whead,
    const float* __restrict__ bhead, const float* __restrict__ v,
    const int* __restrict__ pos, float* __restrict__ out) {
  __shared__ float red[8][32];
  __shared__ float hp[32];
  __shared__ float logits[8];
  int tid = threadIdx.x;
  int row = tid & 31, grp = tid >> 5;
  float s = 0.f;
  for (int b = grp; b < NSPAN_MV; b += 8) s += partPx[b * 32 + row];
  for (int b = grp; b < NSPAN_PV; b += 8) s += partPv[b * 32 + row];
  red[grp][row] = s;
  __syncthreads();
  if (tid < 32) {
    float t = bpol[tid];
    for (int g = 0; g < 8; ++g) t += red[g][tid];
    hp[tid] = fmaxf(t, 0.f);
  }
  __syncthreads();
  if (tid < 8) {
    float t = bhead[tid];
    for (int k = 0; k < 32; ++k) t += Whead[tid * 32 + k] * hp[k];
    logits[tid] = t;
  }
  __syncthreads();
  if (tid == 0) {
    float mx = logits[0];
    for (int j = 1; j < 8; ++j) mx = fmaxf(mx, logits[j]);
    float e[8], sum = 0.f;
    for (int j = 0; j < 8; ++j) {
      e[j] = __expf(logits[j] - mx);
      sum += e[j];
    }
    for (int j = 0; j < 8; ++j) out[j] = e[j] / sum;
    out[8] = v[pos[0] * HW + pos[1]];
  }
}

extern "C" void kernel_launch(void* const* d_in, const int* in_sizes, int n_in,
                              void* d_out, int out_size, void* d_ws,
                              size_t ws_size, hipStream_t stream) {
  const float* x = (const float*)d_in[0];
  const int* pos = (const int*)d_in[1];
  const float* W1 = (const float*)d_in[2];
  const float* b1 = (const float*)d_in[3];
  const float* W2 = (const float*)d_in[4];
  const float* b2 = (const float*)d_in[5];
  const float* Wro = (const float*)d_in[6];
  const float* bro = (const float*)d_in[7];
  const float* Wri = (const float*)d_in[8];
  const float* bri = (const float*)d_in[9];
  const float* Wp = (const float*)d_in[10];
  const float* bp = (const float*)d_in[11];
  const float* Wpol = (const float*)d_in[12];
  const float* bpol = (const float*)d_in[13];
  const float* Whead = (const float*)d_in[14];
  const float* bhead = (const float*)d_in[15];
  float* ws = (float*)d_ws;
  float* out = (float*)d_out;

  float* part1 = ws + WS_PART1;
  float* partPx = ws + WS_PARTPX;
  float* partPv = ws + WS_PARTPV;
  float* h2 = ws + WS_H2;
  float* pbuf = ws + WS_P;
  float* rdbuf = ws + WS_RD;
  float* vbuf = ws + WS_V;

  // K1: W1@x partials AND Wpol x-column partials (independent of v)
  mv_dual<<<1024, 256, 0, stream>>>((const float4*)W1, (const float4*)Wpol,
                                    (const float4*)x, part1, partPx);
  // K2: h1 -> h2
  finish_h<<<1, 256, 0, stream>>>(part1, b1, W2, b2, h2);
  // K3: p, rd
  rop_kernel<<<1024, 256, 0, stream>>>((const float4*)Wro, bro,
                                       (const float4*)Wri, bri,
                                       (const float4*)Wp, bp, h2, pbuf, rdbuf);
  // K4: 10 value-iteration steps, one launch
  valiter_kernel<<<1024, 256, 0, stream>>>(pbuf, rdbuf, vbuf);
  // K5: Wpol v-column partials
  mv_polv<<<256, 256, 0, stream>>>((const float4*)Wpol, (const float4*)vbuf,
                                   partPv);
  // K6: heads + softmax + state value
  finish_pol<<<1, 256, 0, stream>>>(partPx, partPv, bpol, Whead, bhead, vbuf,
                                    pos, out);
}